// Round 7
// baseline (378.860 us; speedup 1.0000x reference)
//
#include <hip/hip_runtime.h>
#include <cstdint>

// ---------------------------------------------------------------------------
// MLA prefill: B=2, S=2048, D=2048, H=16, NOPE=128, ROPE=64, VDIM=128,
// QKD=192, KV_RANK=512. Full (non-causal) attention. FP16 MFMA compute.
// R17 = R15 with attn restructured for 2 blocks/CU WITHOUT shrinking the
//       K-tile (R8's mistake): block = 4 waves / 128 q-rows (wave keeps 32
//       rows, m=2 -> frag reuse preserved), KVBLK stays 64, K/V single-
//       buffered (LDS 61KB -> 2 blocks/CU, two independent barrier domains;
//       exposed staging covered by the sibling block). PSTR=84 and all
//       swizzles identical to the measured-0-conflict R7 layout.
//       GEMMs (counted-vmcnt 256x256 core) and rest identical to R15.
// ---------------------------------------------------------------------------

typedef _Float16 f16;
typedef _Float16 f16x8 __attribute__((ext_vector_type(8)));
typedef _Float16 f16x4 __attribute__((ext_vector_type(4)));
typedef float    f32x4 __attribute__((ext_vector_type(4)));

// 192^-0.5 * log2(e): scores come out pre-scaled in log2 domain -> p = 2^z
#define SCALE_L2E 0.104117550f

__device__ __forceinline__ void gl2lds16(const void* g, void* lds_wave_base) {
  __builtin_amdgcn_global_load_lds(
      (const __attribute__((address_space(1))) uint32_t*)(uintptr_t)g,
      (__attribute__((address_space(3))) uint32_t*)(uint32_t)(uintptr_t)lds_wave_base,
      16, 0, 0);
}

// ---------------------------------------------------------------------------
// converts (wq gets SCALE*log2e folded in)
// + wkv_a (576x2048) -> f16 padded to 768 rows (zeros) in the tail blocks
// ---------------------------------------------------------------------------
__global__ __launch_bounds__(256) void k_cvt(
    const float* __restrict__ x, const float* __restrict__ wq,
    const float* __restrict__ wkvb, const float* __restrict__ wo,
    const float* __restrict__ wkva,
    f16* __restrict__ xb, f16* __restrict__ wqb,
    f16* __restrict__ wkvbb, f16* __restrict__ wob,
    f16* __restrict__ wkvab)
{
  size_t i = ((size_t)blockIdx.x * 256 + threadIdx.x) * 4;
  if (i >= 20971520ull) {           // wkv_a pad region (768x2048 f16 out)
    size_t il = i - 20971520ull;
    int r = (int)(il >> 11);
    f16x4 h;
    if (r < 576) {
      float4 v = *(const float4*)(wkva + il);
      h[0]=(f16)v.x; h[1]=(f16)v.y; h[2]=(f16)v.z; h[3]=(f16)v.w;
    } else { h[0]=h[1]=h[2]=h[3]=(f16)0.f; }
    *(f16x4*)(wkvab + il) = h;
    return;
  }
  const float* src; f16* dst; size_t off; float scl = 1.0f;
  if (i < 8388608ull)            { src = x;    dst = xb;    off = i; }
  else if (i < 14680064ull)      { src = wq;   dst = wqb;   off = i - 8388608ull; scl = SCALE_L2E; }
  else if (i < 16777216ull)      { src = wkvb; dst = wkvbb; off = i - 14680064ull; }
  else                           { src = wo;   dst = wob;   off = i - 16777216ull; }
  float4 v = *(const float4*)(src + off);
  f16x4 h; h[0]=(f16)(v.x*scl); h[1]=(f16)(v.y*scl); h[2]=(f16)(v.z*scl); h[3]=(f16)(v.w*scl);
  *(f16x4*)(dst + off) = h;
}

// ---------------------------------------------------------------------------
// 256x256 NT GEMM core, BK=64, 512 threads = 8 waves (2M x 4N), wave output
// 128x64. LDS 128KB double-buffered, counted-vmcnt pipeline (R15).
// ---------------------------------------------------------------------------
template<class Epi>
__device__ __forceinline__ void gemm256_core(const f16* __restrict__ Ablk,
                                             const f16* __restrict__ Bblk,
                                             int K, Epi epi)
{
  __shared__ __align__(16) f16 As[2][256 * 64];   // 2 x 32 KB
  __shared__ __align__(16) f16 Bs[2][256 * 64];   // 2 x 32 KB

  const int tid  = threadIdx.x;          // 0..511
  const int lane = tid & 63;
  const int wv   = tid >> 6;             // 0..7
  const int wm   = (wv >> 2) * 128;      // 0 / 128
  const int wn   = (wv & 3) * 64;        // 0/64/128/192
  const int lrow = lane & 15;
  const int lk   = lane >> 4;

  f32x4 acc[8][4];
#pragma unroll
  for (int i = 0; i < 8; ++i)
#pragma unroll
    for (int j = 0; j < 4; ++j) acc[i][j] = f32x4{0.f, 0.f, 0.f, 0.f};

  const int NT = K >> 6;

  int s0A[4], s0B[4];
  s0A[0] = tid;        s0A[1] = 1024 + tid;   // G0
  s0A[2] = 512 + tid;  s0A[3] = 1536 + tid;   // G1
  if (wv < 4) { s0B[0] = tid;       s0B[1] = 1024 + tid;    // G2
                s0B[2] = 256 + tid; s0B[3] = 1280 + tid; }  // G3
  else        { s0B[0] = 256 + tid; s0B[1] = 1280 + tid;
                s0B[2] = 512 + tid; s0B[3] = 1536 + tid; }
  const f16* ap[4]; const f16* bp[4]; int alb[4], blb[4];
#pragma unroll
  for (int q = 0; q < 4; ++q) {
    int rA = s0A[q] >> 3, cA = s0A[q] & 7, gA = cA ^ (rA & 7);
    ap[q]  = Ablk + (size_t)rA * K + gA * 8;
    alb[q] = (s0A[q] - lane) * 8;
    int rB = s0B[q] >> 3, cB = s0B[q] & 7, gB = cB ^ (rB & 7);
    bp[q]  = Bblk + (size_t)rB * K + gB * 8;
    blb[q] = (s0B[q] - lane) * 8;
  }

  // prologue: stage tile 0, same group order as steady state (G2,G0,G3,G1)
  gl2lds16(bp[0], (f16*)Bs[0] + blb[0]);
  gl2lds16(bp[1], (f16*)Bs[0] + blb[1]);
  gl2lds16(ap[0], (f16*)As[0] + alb[0]);
  gl2lds16(ap[1], (f16*)As[0] + alb[1]);
  gl2lds16(bp[2], (f16*)Bs[0] + blb[2]);
  gl2lds16(bp[3], (f16*)Bs[0] + blb[3]);
  gl2lds16(ap[2], (f16*)As[0] + alb[2]);
  gl2lds16(ap[3], (f16*)As[0] + alb[3]);

  auto phase = [&](const f16* Ac, const f16* Bc, int mh, int nh) {
    f16x8 af[2][4], bf[2][2];
#pragma unroll
    for (int ks = 0; ks < 2; ++ks) {
#pragma unroll
      for (int i = 0; i < 4; ++i) {
        int ra = wm + mh * 64 + i * 16 + lrow;
        int ca = (ks * 4 + lk) ^ (ra & 7);
        af[ks][i] = *(const f16x8*)(Ac + ra * 64 + ca * 8);
      }
#pragma unroll
      for (int j = 0; j < 2; ++j) {
        int rb = wn + nh * 32 + j * 16 + lrow;
        int cb = (ks * 4 + lk) ^ (rb & 7);
        bf[ks][j] = *(const f16x8*)(Bc + rb * 64 + cb * 8);
      }
    }
    __builtin_amdgcn_s_setprio(1);
#pragma unroll
    for (int ks = 0; ks < 2; ++ks)
#pragma unroll
      for (int i = 0; i < 4; ++i)
#pragma unroll
        for (int j = 0; j < 2; ++j)
          acc[mh * 4 + i][nh * 2 + j] = __builtin_amdgcn_mfma_f32_16x16x32_f16(
              af[ks][i], bf[ks][j], acc[mh * 4 + i][nh * 2 + j], 0, 0, 0);
    __builtin_amdgcn_s_setprio(0);
  };

  for (int t = 0; t < NT; ++t) {
    const int buf = t & 1;
    const f16* Ac = As[buf];
    const f16* Bc = Bs[buf];
    f16* An = (f16*)As[buf ^ 1];
    f16* Bn = (f16*)Bs[buf ^ 1];
    const bool more = (t + 1 < NT);
    const int koff = (t + 1) * 64;

    // ---- p0 (mh0,nh0): needs G0(t),G2(t); leaves G3(t),G1(t) in flight
    asm volatile("s_waitcnt vmcnt(4)" ::: "memory");
    __builtin_amdgcn_s_barrier();
    if (more) {
      gl2lds16(bp[0] + koff, Bn + blb[0]);
      gl2lds16(bp[1] + koff, Bn + blb[1]);
      gl2lds16(ap[0] + koff, An + alb[0]);
      gl2lds16(ap[1] + koff, An + alb[1]);
    }
    phase(Ac, Bc, 0, 0);

    // ---- p1 (mh0,nh1): needs G3(t)
    if (more) asm volatile("s_waitcnt vmcnt(6)" ::: "memory");
    else      asm volatile("s_waitcnt vmcnt(2)" ::: "memory");
    __builtin_amdgcn_s_barrier();
    if (more) {
      gl2lds16(bp[2] + koff, Bn + blb[2]);
      gl2lds16(bp[3] + koff, Bn + blb[3]);
    }
    phase(Ac, Bc, 0, 1);

    // ---- p2 (mh1,nh0): needs G1(t)
    if (more) asm volatile("s_waitcnt vmcnt(6)" ::: "memory");
    else      asm volatile("s_waitcnt vmcnt(0)" ::: "memory");
    __builtin_amdgcn_s_barrier();
    if (more) {
      gl2lds16(ap[2] + koff, An + alb[2]);
      gl2lds16(ap[3] + koff, An + alb[3]);
    }
    phase(Ac, Bc, 1, 0);

    // ---- p3 (mh1,nh1): all data landed
    __builtin_amdgcn_s_barrier();
    phase(Ac, Bc, 1, 1);
  }
  epi(acc, wm, wn, lk, lrow);
}

// fused Q-proj (N=3072, 12 tiles) + KV-a proj (N=768 padded, 3 tiles).
// XCD-grouped remap (240 = 8 XCDs x 30). RoPE fused into the q epilogue.
__global__ __launch_bounds__(512, 2) void k_gemm_qkva(
    const f16* __restrict__ xb, const f16* __restrict__ wqb,
    const f16* __restrict__ wkvab, const float* __restrict__ cosb,
    const float* __restrict__ sinb,
    f16* __restrict__ qraw, f16* __restrict__ kva)
{
  int idx  = blockIdx.y * 15 + blockIdx.x;        // 0..239
  int nidx = (idx & 7) * 30 + (idx >> 3);         // bijective: 240 = 8*30
  int nb = nidx % 15, m0 = (nidx / 15) * 256;
  bool isq = nb < 12;
  const f16* Bblk = isq ? wqb + (size_t)nb * 256 * 2048
                        : wkvab + (size_t)(nb - 12) * 256 * 2048;
  gemm256_core(xb + (size_t)m0 * 2048, Bblk, 2048,
    [&](f32x4 (&acc)[8][4], int wm, int wn, int lk, int lrow) {
      if (isq) {
        f16* Cb = qraw + (size_t)m0 * 3072 + nb * 256;
        int g = nb * 4 + (wn >> 6);
        if (g % 3 == 2) {          // rope slice
#pragma unroll
          for (int I = 0; I < 8; ++I)
#pragma unroll
            for (int rr = 0; rr < 4; ++rr) {
              int row = wm + I * 16 + lk * 4 + rr;
              int s = (m0 + row) & 2047;
              const float* cbp = cosb + (size_t)s * 64;
              const float* sbp = sinb + (size_t)s * 64;
#pragma unroll
              for (int J = 0; J < 4; ++J) {
                int tt = J * 16 + lrow;
                float v  = acc[I][J][rr];
                float pr = acc[I][J ^ 2][rr];
                float o = (J < 2) ? (v * cbp[tt] - pr * sbp[tt])
                                  : (v * cbp[tt] + pr * sbp[tt]);
                Cb[(size_t)row * 3072 + wn + J * 16 + lrow] = (f16)o;
              }
            }
          return;
        }
#pragma unroll
        for (int I = 0; I < 8; ++I)
#pragma unroll
          for (int rr = 0; rr < 4; ++rr) {
            int row = wm + I * 16 + lk * 4 + rr;
#pragma unroll
            for (int J = 0; J < 4; ++J)
              Cb[(size_t)row * 3072 + wn + J * 16 + lrow] = (f16)acc[I][J][rr];
          }
      } else {
        int n0k = (nb - 12) * 256;
        if (n0k + wn >= 640) return;    // zero-pad region, don't store
        f16* Cb = kva + (size_t)m0 * 640 + n0k;
#pragma unroll
        for (int I = 0; I < 8; ++I)
#pragma unroll
          for (int rr = 0; rr < 4; ++rr) {
            int row = wm + I * 16 + lk * 4 + rr;
#pragma unroll
            for (int J = 0; J < 4; ++J)
              Cb[(size_t)row * 640 + wn + J * 16 + lrow] = (f16)acc[I][J][rr];
          }
      }
    });
}

// kv_b proj: each 256-wide n-tile = one head (128 knope | 128 v).
// XCD-grouped remap (256 = 8 x 32).
__global__ __launch_bounds__(512, 2) void k_gemm_kvb(
    const f16* __restrict__ kvn, const f16* __restrict__ wkvbb,
    f16* __restrict__ knope, f16* __restrict__ vf)
{
  int idx  = blockIdx.y * 16 + blockIdx.x;        // 0..255
  int nidx = (idx & 7) * 32 + (idx >> 3);         // bijective: 256 = 8*32
  int hh = nidx & 15, m0 = (nidx >> 4) * 256;
  gemm256_core(kvn + (size_t)m0 * 512, wkvbb + (size_t)hh * 256 * 512, 512,
    [&](f32x4 (&acc)[8][4], int wm, int wn, int lk, int lrow) {
      if (wn >= 128) {   // v half
#pragma unroll
        for (int I = 0; I < 8; ++I) {
          int trow = m0 + wm + I * 16 + lk * 4;
          int bb = trow >> 11, ss = trow & 2047;
#pragma unroll
          for (int J = 0; J < 4; ++J) {
            int vd = (wn - 128) + J * 16 + lrow;
            f16x4 pk;
#pragma unroll
            for (int rr = 0; rr < 4; ++rr) pk[rr] = (f16)acc[I][J][rr];
            *(f16x4*)(vf + ((size_t)(bb * 16 + hh) * 128 + vd) * 2048 + ss) = pk;
          }
        }
      } else {           // knope half
#pragma unroll
        for (int I = 0; I < 8; ++I)
#pragma unroll
          for (int rr = 0; rr < 4; ++rr) {
            int trow = m0 + wm + I * 16 + lk * 4 + rr;
#pragma unroll
            for (int J = 0; J < 4; ++J)
              knope[(size_t)trow * 2048 + hh * 128 + wn + J * 16 + lrow] = (f16)acc[I][J][rr];
          }
      }
    });
}

// ---------------------------------------------------------------------------
// 128x128 NT GEMM core (old structure) for the O-proj.
// ---------------------------------------------------------------------------
template<class Epi>
__device__ __forceinline__ void gemm_core(const f16* __restrict__ Ablk,
                                          const f16* __restrict__ Bblk,
                                          int K, Epi epi)
{
  __shared__ __align__(16) f16 As[128 * 64];
  __shared__ __align__(16) f16 Bs[128 * 64];

  const int tid  = threadIdx.x;
  const int lane = tid & 63;
  const int wv   = tid >> 6;
  const int wm = (wv >> 1) * 64, wn = (wv & 1) * 64;
  const int lrow = lane & 15;
  const int lk   = lane >> 4;

  f32x4 acc[4][4];
#pragma unroll
  for (int i = 0; i < 4; ++i)
#pragma unroll
    for (int j = 0; j < 4; ++j) acc[i][j] = f32x4{0.f, 0.f, 0.f, 0.f};

  for (int k0 = 0; k0 < K; k0 += 64) {
    __syncthreads();
#pragma unroll
    for (int it = 0; it < 4; ++it) {
      int s  = it * 256 + tid;
      int r  = s >> 3, sc = s & 7;
      int gc = sc ^ (r & 7);
      gl2lds16(Ablk + (size_t)r * K + k0 + gc * 8, (f16*)As + (size_t)(it * 256 + wv * 64) * 8);
      gl2lds16(Bblk + (size_t)r * K + k0 + gc * 8, (f16*)Bs + (size_t)(it * 256 + wv * 64) * 8);
    }
    __syncthreads();

#pragma unroll
    for (int ks = 0; ks < 2; ++ks) {
      f16x8 af[4], bf[4];
#pragma unroll
      for (int i = 0; i < 4; ++i) {
        int ra = wm + i * 16 + lrow;
        int ca = (ks * 4 + lk) ^ (ra & 7);
        af[i] = *(const f16x8*)(As + ra * 64 + ca * 8);
        int rb = wn + i * 16 + lrow;
        int cb = (ks * 4 + lk) ^ (rb & 7);
        bf[i] = *(const f16x8*)(Bs + rb * 64 + cb * 8);
      }
#pragma unroll
      for (int i = 0; i < 4; ++i)
#pragma unroll
        for (int j = 0; j < 4; ++j)
          acc[i][j] = __builtin_amdgcn_mfma_f32_16x16x32_f16(af[i], bf[j], acc[i][j], 0, 0, 0);
    }
  }
  epi(acc, wm, wn, lk, lrow);
}

// O-proj, fp32 out
__global__ __launch_bounds__(256, 3) void k_gemm_out(
    const f16* __restrict__ aout, const f16* __restrict__ wob, float* __restrict__ out)
{
  int n0 = blockIdx.x * 128, m0 = blockIdx.y * 128;
  gemm_core(aout + (size_t)m0 * 2048, wob + (size_t)n0 * 2048, 2048,
    [&](f32x4 (&acc)[4][4], int wm, int wn, int lk, int lrow) {
#pragma unroll
      for (int i = 0; i < 4; ++i)
#pragma unroll
        for (int rr = 0; rr < 4; ++rr) {
          int row = m0 + wm + i * 16 + lk * 4 + rr;
#pragma unroll
          for (int j = 0; j < 4; ++j)
            out[(size_t)row * 2048 + n0 + wn + j * 16 + lrow] = acc[i][j][rr];
        }
    });
}

// ---------------------------------------------------------------------------
// RMSNorm over KV_RANK=512 + RoPE on the 64 k_pe dims -> kper
// ---------------------------------------------------------------------------
__global__ __launch_bounds__(256) void k_rmsnorm_rope(
    const f16* __restrict__ kva, const float* __restrict__ w,
    const float* __restrict__ cosb, const float* __restrict__ sinb,
    f16* __restrict__ kvn, f16* __restrict__ kper)
{
  int row = blockIdx.x;
  int s = row & 2047;
  const f16* in = kva + (size_t)row * 640;
  int t = threadIdx.x;
  float v0 = (float)in[t], v1 = (float)in[t + 256];
  float ss = v0 * v0 + v1 * v1;
#pragma unroll
  for (int m = 1; m < 64; m <<= 1) ss += __shfl_xor(ss, m);
  __shared__ float red[4];
  if ((t & 63) == 0) red[t >> 6] = ss;
  __syncthreads();
  float tot = red[0] + red[1] + red[2] + red[3];
  float sc = rsqrtf(tot * (1.0f / 512.0f) + 1e-6f);
  kvn[(size_t)row * 512 + t]       = (f16)(v0 * sc * w[t]);
  kvn[(size_t)row * 512 + t + 256] = (f16)(v1 * sc * w[t + 256]);
  if (t < 32) {
    float a = (float)in[512 + t], bq = (float)in[512 + t + 32];
    float c0 = cosb[s * 64 + t], s0 = sinb[s * 64 + t];
    float c1 = cosb[s * 64 + t + 32], s1 = sinb[s * 64 + t + 32];
    kper[(size_t)row * 64 + t]      = (f16)(a * c0 - bq * s0);
    kper[(size_t)row * 64 + t + 32] = (f16)(bq * c1 + a * s1);
  }
}

// ---------------------------------------------------------------------------
// flash attention R17: 512 blocks of 256 threads (4 waves, 128 q-rows);
// wave owns 32 q-rows (m=2, frag reuse as in R7). KVBLK=64, K/V SINGLE-
// buffered -> LDS 61KB -> 2 blocks/CU (two independent barrier domains;
// each block's exposed staging is covered by the sibling's compute).
// XCD remap: 64 blocks/XCD = 4 (b,h) x 16 q-tiles. Static softmax in log2
// domain. PSTR=84 and all swizzles identical to measured-0-conflict layout.
// ---------------------------------------------------------------------------
#define PSTR 84

__global__ __launch_bounds__(256, 2) void k_attn(
    const f16* __restrict__ qraw, const f16* __restrict__ knope,
    const f16* __restrict__ kper, const f16* __restrict__ vf,
    f16* __restrict__ aout)
{
  int linear = blockIdx.x;          // 0..511
  int xcd  = linear & 7;
  int slot = linear >> 3;           // 0..63
  int hb   = (xcd << 2) | (slot & 3);
  int qt   = slot >> 2;             // 0..15
  int h = hb & 15, b = hb >> 4;
  int q0 = qt * 128;
  int tid = threadIdx.x, lane = tid & 63, wv = tid >> 6;   // wv 0..3
  int lrow = lane & 15, lk = lane >> 4;

  __shared__ __align__(16) f16 Ks[64 * 192];     // 24 KB
  __shared__ __align__(16) f16 Vs[128 * 64];     // 16 KB
  __shared__ __align__(16) f16 Ps[4][32 * PSTR]; // 21 KB
  // total 61 KB -> 2 blocks/CU

  // Q fragments: rows q0 + wv*32 + m*16 + lrow, direct from qraw (pre-scaled)
  f16x8 qfr[2][6];
#pragma unroll
  for (int m = 0; m < 2; ++m) {
    const f16* qb = qraw + ((size_t)(b * 2048 + q0 + wv * 32 + m * 16 + lrow)) * 3072
                    + h * 192 + lk * 8;
#pragma unroll
    for (int ks = 0; ks < 6; ++ks) qfr[m][ks] = *(const f16x8*)(qb + ks * 32);
  }

  f32x4 oacc[2][8];
#pragma unroll
  for (int m = 0; m < 2; ++m)
#pragma unroll
    for (int i = 0; i < 8; ++i) oacc[m][i] = f32x4{0.f, 0.f, 0.f, 0.f};
  float l_st[2][4];
#pragma unroll
  for (int m = 0; m < 2; ++m)
#pragma unroll
    for (int r = 0; r < 4; ++r) l_st[m][r] = 0.f;

  const f16* knb = knope + ((size_t)b * 2048) * 2048 + h * 128;
  const f16* kpb = kper + (size_t)b * 2048 * 64;
  const f16* vb_ = vf + ((size_t)(b * 16 + h)) * 128 * 2048;

  // staging descriptors; 256 threads: K tile = 1536 16B-chunks -> 6 per
  // thread; V tile = 1024 -> 4 per thread. Same swizzles as R7.
  const char* kp_ptr[6]; int kp_step[6];
#pragma unroll
  for (int it = 0; it < 6; ++it) {
    int s = it * 256 + tid;
    int r = s / 24, c = s - r * 24;
    int gc = c ^ (r & 7);
    if (gc < 16) { kp_ptr[it] = (const char*)(knb + (size_t)r * 2048 + gc * 8); kp_step[it] = 64 * 2048 * 2; }
    else         { kp_ptr[it] = (const char*)(kpb + (size_t)r * 64 + (gc - 16) * 8); kp_step[it] = 64 * 64 * 2; }
  }
  const char* vp_ptr[4];
#pragma unroll
  for (int it = 0; it < 4; ++it) {
    int s = it * 256 + tid;
    int r = s >> 3, c = s & 7, gc = c ^ (r & 7);
    vp_ptr[it] = (const char*)(vb_ + (size_t)r * 2048 + gc * 8);
  }

  // preload tile 0
#pragma unroll
  for (int it = 0; it < 6; ++it) {
    gl2lds16(kp_ptr[it], (f16*)Ks + (size_t)(it * 256 + wv * 64) * 8);
    kp_ptr[it] += kp_step[it];
  }
#pragma unroll
  for (int it = 0; it < 4; ++it) {
    gl2lds16(vp_ptr[it], (f16*)Vs + (size_t)(it * 256 + wv * 64) * 8);
    vp_ptr[it] += 64 * 2;
  }
  __syncthreads();   // drain preload (compiler emits vmcnt(0) before barrier)

  for (int t0 = 0; t0 < 2048; t0 += 64) {
    // S = Q K^T : 32 q-rows x 64 keys per wave (B-frags shared across m)
    f32x4 sacc[2][4];
#pragma unroll
    for (int m = 0; m < 2; ++m)
#pragma unroll
      for (int nt = 0; nt < 4; ++nt) sacc[m][nt] = f32x4{0.f, 0.f, 0.f, 0.f};
    __builtin_amdgcn_s_setprio(1);
#pragma unroll
    for (int nt = 0; nt < 4; ++nt) {
      int rb = nt * 16 + lrow;
#pragma unroll
      for (int ks = 0; ks < 6; ++ks) {
        int cc = (ks * 4 + lk) ^ (rb & 7);
        f16x8 bfr = *(const f16x8*)(Ks + rb * 192 + cc * 8);
        sacc[0][nt] = __builtin_amdgcn_mfma_f32_16x16x32_f16(qfr[0][ks], bfr, sacc[0][nt], 0, 0, 0);
        sacc[1][nt] = __builtin_amdgcn_mfma_f32_16x16x32_f16(qfr[1][ks], bfr, sacc[1][nt], 0, 0, 0);
      }
    }
    __builtin_amdgcn_s_setprio(0);

    // static softmax in log2 domain: p = 2^z (TRANS intrinsic)
#pragma unroll
    for (int m = 0; m < 2; ++m) {
#pragma unroll
      for (int r = 0; r < 4; ++r) {
        float p0 = __builtin_amdgcn_exp2f(sacc[m][0][r]);
        float p1 = __builtin_amdgcn_exp2f(sacc[m][1][r]);
        float p2 = __builtin_amdgcn_exp2f(sacc[m][2][r]);
        float p3 = __builtin_amdgcn_exp2f(sacc[m][3][r]);
        l_st[m][r] += (p0 + p1) + (p2 + p3);
        int prow = (m * 16 + lk * 4 + r) * PSTR;
        Ps[wv][prow + 0 * 16 + lrow] = (f16)p0;
        Ps[wv][prow + 1 * 16 + lrow] = (f16)p1;
        Ps[wv][prow + 2 * 16 + lrow] = (f16)p2;
        Ps[wv][prow + 3 * 16 + lrow] = (f16)p3;
      }
    }
    __builtin_amdgcn_s_waitcnt(0xC07F);   // lgkmcnt(0): own P writes visible

    // O += P V  (V^T B-frags shared across m; no alpha rescale needed)
    __builtin_amdgcn_s_setprio(1);
#pragma unroll
    for (int ks2 = 0; ks2 < 2; ++ks2) {
      f16x8 pa0 = *(const f16x8*)(&Ps[wv][(0 * 16 + lrow) * PSTR + ks2 * 32 + lk * 8]);
      f16x8 pa1 = *(const f16x8*)(&Ps[wv][(1 * 16 + lrow) * PSTR + ks2 * 32 + lk * 8]);
#pragma unroll
      for (int nv = 0; nv < 8; ++nv) {
        int rv = nv * 16 + lrow;
        int cc = (ks2 * 4 + lk) ^ (rv & 7);
        f16x8 vbf = *(const f16x8*)(Vs + rv * 64 + cc * 8);
        oacc[0][nv] = __builtin_amdgcn_mfma_f32_16x16x32_f16(pa0, vbf, oacc[0][nv], 0, 0, 0);
        oacc[1][nv] = __builtin_amdgcn_mfma_f32_16x16x32_f16(pa1, vbf, oacc[1][nv], 0, 0, 0);
      }
    }
    __builtin_amdgcn_s_setprio(0);

    if (t0 + 64 < 2048) {
      __syncthreads();   // all waves done reading Ks/Vs for this tile
#pragma unroll
      for (int it = 0; it < 6; ++it) {
        gl2lds16(kp_ptr[it], (f16*)Ks + (size_t)(it * 256 + wv * 64) * 8);
        kp_ptr[it] += kp_step[it];
      }
#pragma unroll
      for (int it = 0; it < 4; ++it) {
        gl2lds16(vp_ptr[it], (f16*)Vs + (size_t)(it * 256 + wv * 64) * 8);
        vp_ptr[it] += 64 * 2;
      }
      __syncthreads();   // drain new tile (vmcnt(0) + barrier)
    }
  }

  // final: reduce l across the 16 lanes of each row, then normalize + store
  float rinv[2][4];
#pragma unroll
  for (int m = 0; m < 2; ++m)
#pragma unroll
    for (int r = 0; r < 4; ++r) {
      float l = l_st[m][r];
#pragma unroll
      for (int msk = 1; msk < 16; msk <<= 1) l += __shfl_xor(l, msk);
      rinv[m][r] = 1.0f / l;
    }
#pragma unroll
  for (int m = 0; m < 2; ++m) {
    f16* ob = aout + ((size_t)(b * 2048 + q0 + wv * 32 + m * 16 + lk * 4)) * 2048
              + h * 128 + lrow;
#pragma unroll
    for (int nv = 0; nv < 8; ++nv)
#pragma unroll
      for (int rr = 0; rr < 4; ++rr)
        ob[(size_t)rr * 2048 + nv * 16] = (f16)(oacc[m][nv][rr] * rinv[m][rr]);
  }
}

// ---------------------------------------------------------------------------
extern "C" void kernel_launch(void* const* d_in, const int* in_sizes, int n_in,
                              void* d_out, int out_size, void* d_ws, size_t ws_size,
                              hipStream_t stream)
{
  const float* x    = (const float*)d_in[0];
  const float* cosb = (const float*)d_in[1];
  const float* sinb = (const float*)d_in[2];
  const float* wq   = (const float*)d_in[3];
  const float* wkva = (const float*)d_in[4];
  const float* knw  = (const float*)d_in[5];
  const float* wkvb = (const float*)d_in[6];
  const float* wo   = (const float*)d_in[7];
  float* out = (float*)d_out;

  char* p = (char*)d_ws;
  auto take = [&](size_t elems) { char* r = p; p += (elems * 2 + 255) & ~(size_t)255; return r; };
  f16* xb    = (f16*)take(8388608ull);    // x f16          (4096x2048)
  f16* wqb   = (f16*)take(6291456ull);    // wq f16 *SCALE  (3072x2048)
  f16* wkvab = (f16*)take(1572864ull);    // wkv_a padded   (768x2048)
  f16* wkvbb = (f16*)take(2097152ull);    // wkv_b f16      (4096x512)
  f16* wob   = (f16*)take(4194304ull);    // wo f16         (2048x2048)
  f16* qraw  = (f16*)take(12582912ull);   // q proj, roped in epilogue (4096x3072)
  f16* kva   = (f16*)take(2621440ull);    // kv_a out       (4096x640)
  f16* kvn   = (f16*)take(2097152ull);    // rmsnormed kv   (4096x512)
  f16* kper  = (f16*)take(262144ull);     // roped k_pe     (4096x64)
  f16* knope = (f16*)take(8388608ull);    // k_nope         (4096x2048)
  f16* vf    = (f16*)take(8388608ull);    // V^T (b,h,128,2048)
  f16* aout  = (f16*)take(8388608ull);    // attn out       (4096x2048)

  k_cvt<<<22016, 256, 0, stream>>>(x, wq, wkvb, wo, wkva, xb, wqb, wkvbb, wob, wkvab);
  k_gemm_qkva<<<dim3(15, 16), 512, 0, stream>>>(xb, wqb, wkvab, cosb, sinb, qraw, kva);
  k_rmsnorm_rope<<<4096, 256, 0, stream>>>(kva, knw, cosb, sinb, kvn, kper);
  k_gemm_kvb<<<dim3(16, 16), 512, 0, stream>>>(kvn, wkvbb, knope, vf);
  k_attn<<<dim3(512), 256, 0, stream>>>(qraw, knope, kper, vf, aout);
  k_gemm_out<<<dim3(16, 32), 256, 0, stream>>>(aout, wob, out);
}

// Round 11
// 351.616 us; speedup vs baseline: 1.0775x; 1.0775x over previous
//
#include <hip/hip_runtime.h>
#include <cstdint>

// ---------------------------------------------------------------------------
// MLA prefill: B=2, S=2048, D=2048, H=16, NOPE=128, ROPE=64, VDIM=128,
// QKD=192, KV_RANK=512. Full (non-causal) attention. FP16 MFMA compute.
// R19 (3rd resubmit; three consecutive GPUAcquisitionTimeouts, never measured)
//     = R15 (best verified: 359.5us) + XCD-grouped O-proj grid.
//       attn = R7-structure dbuf (verified 101.4us, 0 bank conflicts).
//       GEMMs qkva/kvb = 256x256 counted-vmcnt core (R15).
//       R17 lesson: 2blk x 4w = 8 waves/CU = same occupancy as 1blk x 8w;
//       attn occupancy is LDS-bound at 8 waves/CU in all layouts with Ps.
// ---------------------------------------------------------------------------

typedef _Float16 f16;
typedef _Float16 f16x8 __attribute__((ext_vector_type(8)));
typedef _Float16 f16x4 __attribute__((ext_vector_type(4)));
typedef float    f32x4 __attribute__((ext_vector_type(4)));

// 192^-0.5 * log2(e): scores come out pre-scaled in log2 domain -> p = 2^z
#define SCALE_L2E 0.104117550f

__device__ __forceinline__ void gl2lds16(const void* g, void* lds_wave_base) {
  __builtin_amdgcn_global_load_lds(
      (const __attribute__((address_space(1))) uint32_t*)(uintptr_t)g,
      (__attribute__((address_space(3))) uint32_t*)(uint32_t)(uintptr_t)lds_wave_base,
      16, 0, 0);
}

// ---------------------------------------------------------------------------
// converts (wq gets SCALE*log2e folded in)
// + wkv_a (576x2048) -> f16 padded to 768 rows (zeros) in the tail blocks
// ---------------------------------------------------------------------------
__global__ __launch_bounds__(256) void k_cvt(
    const float* __restrict__ x, const float* __restrict__ wq,
    const float* __restrict__ wkvb, const float* __restrict__ wo,
    const float* __restrict__ wkva,
    f16* __restrict__ xb, f16* __restrict__ wqb,
    f16* __restrict__ wkvbb, f16* __restrict__ wob,
    f16* __restrict__ wkvab)
{
  size_t i = ((size_t)blockIdx.x * 256 + threadIdx.x) * 4;
  if (i >= 20971520ull) {           // wkv_a pad region (768x2048 f16 out)
    size_t il = i - 20971520ull;
    int r = (int)(il >> 11);
    f16x4 h;
    if (r < 576) {
      float4 v = *(const float4*)(wkva + il);
      h[0]=(f16)v.x; h[1]=(f16)v.y; h[2]=(f16)v.z; h[3]=(f16)v.w;
    } else { h[0]=h[1]=h[2]=h[3]=(f16)0.f; }
    *(f16x4*)(wkvab + il) = h;
    return;
  }
  const float* src; f16* dst; size_t off; float scl = 1.0f;
  if (i < 8388608ull)            { src = x;    dst = xb;    off = i; }
  else if (i < 14680064ull)      { src = wq;   dst = wqb;   off = i - 8388608ull; scl = SCALE_L2E; }
  else if (i < 16777216ull)      { src = wkvb; dst = wkvbb; off = i - 14680064ull; }
  else                           { src = wo;   dst = wob;   off = i - 16777216ull; }
  float4 v = *(const float4*)(src + off);
  f16x4 h; h[0]=(f16)(v.x*scl); h[1]=(f16)(v.y*scl); h[2]=(f16)(v.z*scl); h[3]=(f16)(v.w*scl);
  *(f16x4*)(dst + off) = h;
}

// ---------------------------------------------------------------------------
// 256x256 NT GEMM core, BK=64, 512 threads = 8 waves (2M x 4N), wave output
// 128x64. LDS 128KB double-buffered, counted-vmcnt pipeline (R15).
// ---------------------------------------------------------------------------
template<class Epi>
__device__ __forceinline__ void gemm256_core(const f16* __restrict__ Ablk,
                                             const f16* __restrict__ Bblk,
                                             int K, Epi epi)
{
  __shared__ __align__(16) f16 As[2][256 * 64];   // 2 x 32 KB
  __shared__ __align__(16) f16 Bs[2][256 * 64];   // 2 x 32 KB

  const int tid  = threadIdx.x;          // 0..511
  const int lane = tid & 63;
  const int wv   = tid >> 6;             // 0..7
  const int wm   = (wv >> 2) * 128;      // 0 / 128
  const int wn   = (wv & 3) * 64;        // 0/64/128/192
  const int lrow = lane & 15;
  const int lk   = lane >> 4;

  f32x4 acc[8][4];
#pragma unroll
  for (int i = 0; i < 8; ++i)
#pragma unroll
    for (int j = 0; j < 4; ++j) acc[i][j] = f32x4{0.f, 0.f, 0.f, 0.f};

  const int NT = K >> 6;

  int s0A[4], s0B[4];
  s0A[0] = tid;        s0A[1] = 1024 + tid;   // G0
  s0A[2] = 512 + tid;  s0A[3] = 1536 + tid;   // G1
  if (wv < 4) { s0B[0] = tid;       s0B[1] = 1024 + tid;    // G2
                s0B[2] = 256 + tid; s0B[3] = 1280 + tid; }  // G3
  else        { s0B[0] = 256 + tid; s0B[1] = 1280 + tid;
                s0B[2] = 512 + tid; s0B[3] = 1536 + tid; }
  const f16* ap[4]; const f16* bp[4]; int alb[4], blb[4];
#pragma unroll
  for (int q = 0; q < 4; ++q) {
    int rA = s0A[q] >> 3, cA = s0A[q] & 7, gA = cA ^ (rA & 7);
    ap[q]  = Ablk + (size_t)rA * K + gA * 8;
    alb[q] = (s0A[q] - lane) * 8;
    int rB = s0B[q] >> 3, cB = s0B[q] & 7, gB = cB ^ (rB & 7);
    bp[q]  = Bblk + (size_t)rB * K + gB * 8;
    blb[q] = (s0B[q] - lane) * 8;
  }

  // prologue: stage tile 0, same group order as steady state (G2,G0,G3,G1)
  gl2lds16(bp[0], (f16*)Bs[0] + blb[0]);
  gl2lds16(bp[1], (f16*)Bs[0] + blb[1]);
  gl2lds16(ap[0], (f16*)As[0] + alb[0]);
  gl2lds16(ap[1], (f16*)As[0] + alb[1]);
  gl2lds16(bp[2], (f16*)Bs[0] + blb[2]);
  gl2lds16(bp[3], (f16*)Bs[0] + blb[3]);
  gl2lds16(ap[2], (f16*)As[0] + alb[2]);
  gl2lds16(ap[3], (f16*)As[0] + alb[3]);

  auto phase = [&](const f16* Ac, const f16* Bc, int mh, int nh) {
    f16x8 af[2][4], bf[2][2];
#pragma unroll
    for (int ks = 0; ks < 2; ++ks) {
#pragma unroll
      for (int i = 0; i < 4; ++i) {
        int ra = wm + mh * 64 + i * 16 + lrow;
        int ca = (ks * 4 + lk) ^ (ra & 7);
        af[ks][i] = *(const f16x8*)(Ac + ra * 64 + ca * 8);
      }
#pragma unroll
      for (int j = 0; j < 2; ++j) {
        int rb = wn + nh * 32 + j * 16 + lrow;
        int cb = (ks * 4 + lk) ^ (rb & 7);
        bf[ks][j] = *(const f16x8*)(Bc + rb * 64 + cb * 8);
      }
    }
    __builtin_amdgcn_s_setprio(1);
#pragma unroll
    for (int ks = 0; ks < 2; ++ks)
#pragma unroll
      for (int i = 0; i < 4; ++i)
#pragma unroll
        for (int j = 0; j < 2; ++j)
          acc[mh * 4 + i][nh * 2 + j] = __builtin_amdgcn_mfma_f32_16x16x32_f16(
              af[ks][i], bf[ks][j], acc[mh * 4 + i][nh * 2 + j], 0, 0, 0);
    __builtin_amdgcn_s_setprio(0);
  };

  for (int t = 0; t < NT; ++t) {
    const int buf = t & 1;
    const f16* Ac = As[buf];
    const f16* Bc = Bs[buf];
    f16* An = (f16*)As[buf ^ 1];
    f16* Bn = (f16*)Bs[buf ^ 1];
    const bool more = (t + 1 < NT);
    const int koff = (t + 1) * 64;

    // ---- p0 (mh0,nh0): needs G0(t),G2(t); leaves G3(t),G1(t) in flight
    asm volatile("s_waitcnt vmcnt(4)" ::: "memory");
    __builtin_amdgcn_s_barrier();
    if (more) {
      gl2lds16(bp[0] + koff, Bn + blb[0]);
      gl2lds16(bp[1] + koff, Bn + blb[1]);
      gl2lds16(ap[0] + koff, An + alb[0]);
      gl2lds16(ap[1] + koff, An + alb[1]);
    }
    phase(Ac, Bc, 0, 0);

    // ---- p1 (mh0,nh1): needs G3(t)
    if (more) asm volatile("s_waitcnt vmcnt(6)" ::: "memory");
    else      asm volatile("s_waitcnt vmcnt(2)" ::: "memory");
    __builtin_amdgcn_s_barrier();
    if (more) {
      gl2lds16(bp[2] + koff, Bn + blb[2]);
      gl2lds16(bp[3] + koff, Bn + blb[3]);
    }
    phase(Ac, Bc, 0, 1);

    // ---- p2 (mh1,nh0): needs G1(t)
    if (more) asm volatile("s_waitcnt vmcnt(6)" ::: "memory");
    else      asm volatile("s_waitcnt vmcnt(0)" ::: "memory");
    __builtin_amdgcn_s_barrier();
    if (more) {
      gl2lds16(ap[2] + koff, An + alb[2]);
      gl2lds16(ap[3] + koff, An + alb[3]);
    }
    phase(Ac, Bc, 1, 0);

    // ---- p3 (mh1,nh1): all data landed
    __builtin_amdgcn_s_barrier();
    phase(Ac, Bc, 1, 1);
  }
  epi(acc, wm, wn, lk, lrow);
}

// fused Q-proj (N=3072, 12 tiles) + KV-a proj (N=768 padded, 3 tiles).
// XCD-grouped remap (240 = 8 XCDs x 30). RoPE fused into the q epilogue.
__global__ __launch_bounds__(512, 2) void k_gemm_qkva(
    const f16* __restrict__ xb, const f16* __restrict__ wqb,
    const f16* __restrict__ wkvab, const float* __restrict__ cosb,
    const float* __restrict__ sinb,
    f16* __restrict__ qraw, f16* __restrict__ kva)
{
  int idx  = blockIdx.y * 15 + blockIdx.x;        // 0..239
  int nidx = (idx & 7) * 30 + (idx >> 3);         // bijective: 240 = 8*30
  int nb = nidx % 15, m0 = (nidx / 15) * 256;
  bool isq = nb < 12;
  const f16* Bblk = isq ? wqb + (size_t)nb * 256 * 2048
                        : wkvab + (size_t)(nb - 12) * 256 * 2048;
  gemm256_core(xb + (size_t)m0 * 2048, Bblk, 2048,
    [&](f32x4 (&acc)[8][4], int wm, int wn, int lk, int lrow) {
      if (isq) {
        f16* Cb = qraw + (size_t)m0 * 3072 + nb * 256;
        int g = nb * 4 + (wn >> 6);
        if (g % 3 == 2) {          // rope slice
#pragma unroll
          for (int I = 0; I < 8; ++I)
#pragma unroll
            for (int rr = 0; rr < 4; ++rr) {
              int row = wm + I * 16 + lk * 4 + rr;
              int s = (m0 + row) & 2047;
              const float* cbp = cosb + (size_t)s * 64;
              const float* sbp = sinb + (size_t)s * 64;
#pragma unroll
              for (int J = 0; J < 4; ++J) {
                int tt = J * 16 + lrow;
                float v  = acc[I][J][rr];
                float pr = acc[I][J ^ 2][rr];
                float o = (J < 2) ? (v * cbp[tt] - pr * sbp[tt])
                                  : (v * cbp[tt] + pr * sbp[tt]);
                Cb[(size_t)row * 3072 + wn + J * 16 + lrow] = (f16)o;
              }
            }
          return;
        }
#pragma unroll
        for (int I = 0; I < 8; ++I)
#pragma unroll
          for (int rr = 0; rr < 4; ++rr) {
            int row = wm + I * 16 + lk * 4 + rr;
#pragma unroll
            for (int J = 0; J < 4; ++J)
              Cb[(size_t)row * 3072 + wn + J * 16 + lrow] = (f16)acc[I][J][rr];
          }
      } else {
        int n0k = (nb - 12) * 256;
        if (n0k + wn >= 640) return;    // zero-pad region, don't store
        f16* Cb = kva + (size_t)m0 * 640 + n0k;
#pragma unroll
        for (int I = 0; I < 8; ++I)
#pragma unroll
          for (int rr = 0; rr < 4; ++rr) {
            int row = wm + I * 16 + lk * 4 + rr;
#pragma unroll
            for (int J = 0; J < 4; ++J)
              Cb[(size_t)row * 640 + wn + J * 16 + lrow] = (f16)acc[I][J][rr];
          }
      }
    });
}

// kv_b proj: each 256-wide n-tile = one head (128 knope | 128 v).
// XCD-grouped remap (256 = 8 x 32).
__global__ __launch_bounds__(512, 2) void k_gemm_kvb(
    const f16* __restrict__ kvn, const f16* __restrict__ wkvbb,
    f16* __restrict__ knope, f16* __restrict__ vf)
{
  int idx  = blockIdx.y * 16 + blockIdx.x;        // 0..255
  int nidx = (idx & 7) * 32 + (idx >> 3);         // bijective: 256 = 8*32
  int hh = nidx & 15, m0 = (nidx >> 4) * 256;
  gemm256_core(kvn + (size_t)m0 * 512, wkvbb + (size_t)hh * 256 * 512, 512,
    [&](f32x4 (&acc)[8][4], int wm, int wn, int lk, int lrow) {
      if (wn >= 128) {   // v half
#pragma unroll
        for (int I = 0; I < 8; ++I) {
          int trow = m0 + wm + I * 16 + lk * 4;
          int bb = trow >> 11, ss = trow & 2047;
#pragma unroll
          for (int J = 0; J < 4; ++J) {
            int vd = (wn - 128) + J * 16 + lrow;
            f16x4 pk;
#pragma unroll
            for (int rr = 0; rr < 4; ++rr) pk[rr] = (f16)acc[I][J][rr];
            *(f16x4*)(vf + ((size_t)(bb * 16 + hh) * 128 + vd) * 2048 + ss) = pk;
          }
        }
      } else {           // knope half
#pragma unroll
        for (int I = 0; I < 8; ++I)
#pragma unroll
          for (int rr = 0; rr < 4; ++rr) {
            int trow = m0 + wm + I * 16 + lk * 4 + rr;
#pragma unroll
            for (int J = 0; J < 4; ++J)
              knope[(size_t)trow * 2048 + hh * 128 + wn + J * 16 + lrow] = (f16)acc[I][J][rr];
          }
      }
    });
}

// ---------------------------------------------------------------------------
// 128x128 NT GEMM core (old structure) for the O-proj.
// ---------------------------------------------------------------------------
template<class Epi>
__device__ __forceinline__ void gemm_core(const f16* __restrict__ Ablk,
                                          const f16* __restrict__ Bblk,
                                          int K, Epi epi)
{
  __shared__ __align__(16) f16 As[128 * 64];
  __shared__ __align__(16) f16 Bs[128 * 64];

  const int tid  = threadIdx.x;
  const int lane = tid & 63;
  const int wv   = tid >> 6;
  const int wm = (wv >> 1) * 64, wn = (wv & 1) * 64;
  const int lrow = lane & 15;
  const int lk   = lane >> 4;

  f32x4 acc[4][4];
#pragma unroll
  for (int i = 0; i < 4; ++i)
#pragma unroll
    for (int j = 0; j < 4; ++j) acc[i][j] = f32x4{0.f, 0.f, 0.f, 0.f};

  for (int k0 = 0; k0 < K; k0 += 64) {
    __syncthreads();
#pragma unroll
    for (int it = 0; it < 4; ++it) {
      int s  = it * 256 + tid;
      int r  = s >> 3, sc = s & 7;
      int gc = sc ^ (r & 7);
      gl2lds16(Ablk + (size_t)r * K + k0 + gc * 8, (f16*)As + (size_t)(it * 256 + wv * 64) * 8);
      gl2lds16(Bblk + (size_t)r * K + k0 + gc * 8, (f16*)Bs + (size_t)(it * 256 + wv * 64) * 8);
    }
    __syncthreads();

#pragma unroll
    for (int ks = 0; ks < 2; ++ks) {
      f16x8 af[4], bf[4];
#pragma unroll
      for (int i = 0; i < 4; ++i) {
        int ra = wm + i * 16 + lrow;
        int ca = (ks * 4 + lk) ^ (ra & 7);
        af[i] = *(const f16x8*)(As + ra * 64 + ca * 8);
        int rb = wn + i * 16 + lrow;
        int cb = (ks * 4 + lk) ^ (rb & 7);
        bf[i] = *(const f16x8*)(Bs + rb * 64 + cb * 8);
      }
#pragma unroll
      for (int i = 0; i < 4; ++i)
#pragma unroll
        for (int j = 0; j < 4; ++j)
          acc[i][j] = __builtin_amdgcn_mfma_f32_16x16x32_f16(af[i], bf[j], acc[i][j], 0, 0, 0);
    }
  }
  epi(acc, wm, wn, lk, lrow);
}

// O-proj, fp32 out. XCD-grouped grid (512 = 8 x 64): each XCD owns 4 m-rows
// x all 16 n-tiles -> 4 A-panels (2MB) L2-resident with 16x reuse.
__global__ __launch_bounds__(256, 3) void k_gemm_out(
    const f16* __restrict__ aout, const f16* __restrict__ wob, float* __restrict__ out)
{
  int idx  = blockIdx.y * 16 + blockIdx.x;        // 0..511
  int nidx = (idx & 7) * 64 + (idx >> 3);         // bijective: 512 = 8*64
  int n0 = (nidx & 15) * 128, m0 = (nidx >> 4) * 128;
  gemm_core(aout + (size_t)m0 * 2048, wob + (size_t)n0 * 2048, 2048,
    [&](f32x4 (&acc)[4][4], int wm, int wn, int lk, int lrow) {
#pragma unroll
      for (int i = 0; i < 4; ++i)
#pragma unroll
        for (int rr = 0; rr < 4; ++rr) {
          int row = m0 + wm + i * 16 + lk * 4 + rr;
#pragma unroll
          for (int j = 0; j < 4; ++j)
            out[(size_t)row * 2048 + n0 + wn + j * 16 + lrow] = acc[i][j][rr];
        }
    });
}

// ---------------------------------------------------------------------------
// RMSNorm over KV_RANK=512 + RoPE on the 64 k_pe dims -> kper
// ---------------------------------------------------------------------------
__global__ __launch_bounds__(256) void k_rmsnorm_rope(
    const f16* __restrict__ kva, const float* __restrict__ w,
    const float* __restrict__ cosb, const float* __restrict__ sinb,
    f16* __restrict__ kvn, f16* __restrict__ kper)
{
  int row = blockIdx.x;
  int s = row & 2047;
  const f16* in = kva + (size_t)row * 640;
  int t = threadIdx.x;
  float v0 = (float)in[t], v1 = (float)in[t + 256];
  float ss = v0 * v0 + v1 * v1;
#pragma unroll
  for (int m = 1; m < 64; m <<= 1) ss += __shfl_xor(ss, m);
  __shared__ float red[4];
  if ((t & 63) == 0) red[t >> 6] = ss;
  __syncthreads();
  float tot = red[0] + red[1] + red[2] + red[3];
  float sc = rsqrtf(tot * (1.0f / 512.0f) + 1e-6f);
  kvn[(size_t)row * 512 + t]       = (f16)(v0 * sc * w[t]);
  kvn[(size_t)row * 512 + t + 256] = (f16)(v1 * sc * w[t + 256]);
  if (t < 32) {
    float a = (float)in[512 + t], bq = (float)in[512 + t + 32];
    float c0 = cosb[s * 64 + t], s0 = sinb[s * 64 + t];
    float c1 = cosb[s * 64 + t + 32], s1 = sinb[s * 64 + t + 32];
    kper[(size_t)row * 64 + t]      = (f16)(a * c0 - bq * s0);
    kper[(size_t)row * 64 + t + 32] = (f16)(bq * c1 + a * s1);
  }
}

// ---------------------------------------------------------------------------
// flash attention (R7 structure, verified ~101us / 0 bank conflicts):
// block = (q-tile 256, h, b) remapped so the 8 q-tile blocks sharing one
// (b,h) K/V stream land on ONE XCD. 512 threads = 8 waves, wave owns 32
// q-rows. Double-buffered K/V, ONE barrier per 64-key iteration. Static
// softmax in log2 domain (p = 2^z, scores pre-scaled by 192^-0.5*log2e).
// LDS = 2*24K (Ks) + 2*16K (Vs) + 42K (Ps) = 124.9 KB -> 1 block/CU.
// ---------------------------------------------------------------------------
#define PSTR 84   // Ps row stride (f16): measured 0 bank conflicts

__global__ __launch_bounds__(512, 2) void k_attn(
    const f16* __restrict__ qraw, const f16* __restrict__ knope,
    const f16* __restrict__ kper, const f16* __restrict__ vf,
    f16* __restrict__ aout)
{
  // XCD-grouping remap: 256 blocks -> 32 per XCD = 4 (b,h) x 8 q-tiles.
  int linear = blockIdx.x;
  int xcd  = linear & 7;
  int slot = linear >> 3;
  int hb   = (xcd << 2) | (slot & 3);
  int qt   = slot >> 2;
  int h = hb & 15, b = hb >> 4;
  int q0 = qt * 256;
  int tid = threadIdx.x, lane = tid & 63, wv = tid >> 6;
  int lrow = lane & 15, lk = lane >> 4;

  __shared__ __align__(16) f16 Ks[2][64 * 192];     // 2 x 24 KB
  __shared__ __align__(16) f16 Vs[2][128 * 64];     // 2 x 16 KB
  __shared__ __align__(16) f16 Ps[8][32 * PSTR];    // 42 KB

  // Q fragments: rows q0 + wv*32 + m*16 + lrow, direct from qraw (pre-scaled)
  f16x8 qfr[2][6];
#pragma unroll
  for (int m = 0; m < 2; ++m) {
    const f16* qb = qraw + ((size_t)(b * 2048 + q0 + wv * 32 + m * 16 + lrow)) * 3072
                    + h * 192 + lk * 8;
#pragma unroll
    for (int ks = 0; ks < 6; ++ks) qfr[m][ks] = *(const f16x8*)(qb + ks * 32);
  }

  f32x4 oacc[2][8];
#pragma unroll
  for (int m = 0; m < 2; ++m)
#pragma unroll
    for (int i = 0; i < 8; ++i) oacc[m][i] = f32x4{0.f, 0.f, 0.f, 0.f};
  float l_st[2][4];
#pragma unroll
  for (int m = 0; m < 2; ++m)
#pragma unroll
    for (int r = 0; r < 4; ++r) l_st[m][r] = 0.f;

  const f16* knb = knope + ((size_t)b * 2048) * 2048 + h * 128;
  const f16* kpb = kper + (size_t)b * 2048 * 64;
  const f16* vb_ = vf + ((size_t)(b * 16 + h)) * 128 * 2048;

  // staging descriptors; 512 threads: K tile = 1536 16B-chunks -> 3 per
  // thread; V tile = 1024 -> 2 per thread.
  const char* kp_ptr[3]; int kp_step[3];
#pragma unroll
  for (int it = 0; it < 3; ++it) {
    int s = it * 512 + tid;
    int r = s / 24, c = s - r * 24;
    int gc = c ^ (r & 7);
    if (gc < 16) { kp_ptr[it] = (const char*)(knb + (size_t)r * 2048 + gc * 8); kp_step[it] = 64 * 2048 * 2; }
    else         { kp_ptr[it] = (const char*)(kpb + (size_t)r * 64 + (gc - 16) * 8); kp_step[it] = 64 * 64 * 2; }
  }
  const char* vp_ptr[2];
#pragma unroll
  for (int it = 0; it < 2; ++it) {
    int s = it * 512 + tid;
    int r = s >> 3, c = s & 7, gc = c ^ (r & 7);
    vp_ptr[it] = (const char*)(vb_ + (size_t)r * 2048 + gc * 8);
  }

  // preload tile 0 into buffer 0
#pragma unroll
  for (int it = 0; it < 3; ++it) {
    gl2lds16(kp_ptr[it], (f16*)Ks[0] + (size_t)(it * 512 + wv * 64) * 8);
    kp_ptr[it] += kp_step[it];
  }
#pragma unroll
  for (int it = 0; it < 2; ++it) {
    gl2lds16(vp_ptr[it], (f16*)Vs[0] + (size_t)(it * 512 + wv * 64) * 8);
    vp_ptr[it] += 64 * 2;
  }

  int cur = 0;
  for (int t0 = 0; t0 < 2048; t0 += 64) {
    __syncthreads();   // drains current-buffer loads (vmcnt0) + syncs readers
    if (t0 + 64 < 2048) {    // prefetch next tile into the other buffer
#pragma unroll
      for (int it = 0; it < 3; ++it) {
        gl2lds16(kp_ptr[it], (f16*)Ks[cur ^ 1] + (size_t)(it * 512 + wv * 64) * 8);
        kp_ptr[it] += kp_step[it];
      }
#pragma unroll
      for (int it = 0; it < 2; ++it) {
        gl2lds16(vp_ptr[it], (f16*)Vs[cur ^ 1] + (size_t)(it * 512 + wv * 64) * 8);
        vp_ptr[it] += 64 * 2;
      }
    }
    const f16* Kc = Ks[cur];
    const f16* Vc = Vs[cur];

    // S = Q K^T : 32 q-rows x 64 keys per wave (B-frags shared across m)
    f32x4 sacc[2][4];
#pragma unroll
    for (int m = 0; m < 2; ++m)
#pragma unroll
      for (int nt = 0; nt < 4; ++nt) sacc[m][nt] = f32x4{0.f, 0.f, 0.f, 0.f};
    __builtin_amdgcn_s_setprio(1);
#pragma unroll
    for (int nt = 0; nt < 4; ++nt) {
      int rb = nt * 16 + lrow;
#pragma unroll
      for (int ks = 0; ks < 6; ++ks) {
        int cc = (ks * 4 + lk) ^ (rb & 7);
        f16x8 bfr = *(const f16x8*)(Kc + rb * 192 + cc * 8);
        sacc[0][nt] = __builtin_amdgcn_mfma_f32_16x16x32_f16(qfr[0][ks], bfr, sacc[0][nt], 0, 0, 0);
        sacc[1][nt] = __builtin_amdgcn_mfma_f32_16x16x32_f16(qfr[1][ks], bfr, sacc[1][nt], 0, 0, 0);
      }
    }
    __builtin_amdgcn_s_setprio(0);

    // static softmax in log2 domain: p = 2^z (TRANS intrinsic)
#pragma unroll
    for (int m = 0; m < 2; ++m) {
#pragma unroll
      for (int r = 0; r < 4; ++r) {
        float p0 = __builtin_amdgcn_exp2f(sacc[m][0][r]);
        float p1 = __builtin_amdgcn_exp2f(sacc[m][1][r]);
        float p2 = __builtin_amdgcn_exp2f(sacc[m][2][r]);
        float p3 = __builtin_amdgcn_exp2f(sacc[m][3][r]);
        l_st[m][r] += (p0 + p1) + (p2 + p3);
        int prow = (m * 16 + lk * 4 + r) * PSTR;
        Ps[wv][prow + 0 * 16 + lrow] = (f16)p0;
        Ps[wv][prow + 1 * 16 + lrow] = (f16)p1;
        Ps[wv][prow + 2 * 16 + lrow] = (f16)p2;
        Ps[wv][prow + 3 * 16 + lrow] = (f16)p3;
      }
    }
    __builtin_amdgcn_s_waitcnt(0xC07F);   // lgkmcnt(0): own P writes visible

    // O += P V  (V^T B-frags shared across m; no alpha rescale needed)
    __builtin_amdgcn_s_setprio(1);
#pragma unroll
    for (int ks2 = 0; ks2 < 2; ++ks2) {
      f16x8 pa0 = *(const f16x8*)(&Ps[wv][(0 * 16 + lrow) * PSTR + ks2 * 32 + lk * 8]);
      f16x8 pa1 = *(const f16x8*)(&Ps[wv][(1 * 16 + lrow) * PSTR + ks2 * 32 + lk * 8]);
#pragma unroll
      for (int nv = 0; nv < 8; ++nv) {
        int rv = nv * 16 + lrow;
        int cc = (ks2 * 4 + lk) ^ (rv & 7);
        f16x8 vbf = *(const f16x8*)(Vc + rv * 64 + cc * 8);
        oacc[0][nv] = __builtin_amdgcn_mfma_f32_16x16x32_f16(pa0, vbf, oacc[0][nv], 0, 0, 0);
        oacc[1][nv] = __builtin_amdgcn_mfma_f32_16x16x32_f16(pa1, vbf, oacc[1][nv], 0, 0, 0);
      }
    }
    __builtin_amdgcn_s_setprio(0);
    cur ^= 1;
  }

  // final: reduce l across the 16 lanes of each row, then normalize + store
  float rinv[2][4];
#pragma unroll
  for (int m = 0; m < 2; ++m)
#pragma unroll
    for (int r = 0; r < 4; ++r) {
      float l = l_st[m][r];
#pragma unroll
      for (int msk = 1; msk < 16; msk <<= 1) l += __shfl_xor(l, msk);
      rinv[m][r] = 1.0f / l;
    }
#pragma unroll
  for (int m = 0; m < 2; ++m) {
    f16* ob = aout + ((size_t)(b * 2048 + q0 + wv * 32 + m * 16 + lk * 4)) * 2048
              + h * 128 + lrow;
#pragma unroll
    for (int nv = 0; nv < 8; ++nv)
#pragma unroll
      for (int rr = 0; rr < 4; ++rr)
        ob[(size_t)rr * 2048 + nv * 16] = (f16)(oacc[m][nv][rr] * rinv[m][rr]);
  }
}

// ---------------------------------------------------------------------------
extern "C" void kernel_launch(void* const* d_in, const int* in_sizes, int n_in,
                              void* d_out, int out_size, void* d_ws, size_t ws_size,
                              hipStream_t stream)
{
  const float* x    = (const float*)d_in[0];
  const float* cosb = (const float*)d_in[1];
  const float* sinb = (const float*)d_in[2];
  const float* wq   = (const float*)d_in[3];
  const float* wkva = (const float*)d_in[4];
  const float* knw  = (const float*)d_in[5];
  const float* wkvb = (const float*)d_in[6];
  const float* wo   = (const float*)d_in[7];
  float* out = (float*)d_out;

  char* p = (char*)d_ws;
  auto take = [&](size_t elems) { char* r = p; p += (elems * 2 + 255) & ~(size_t)255; return r; };
  f16* xb    = (f16*)take(8388608ull);    // x f16          (4096x2048)
  f16* wqb   = (f16*)take(6291456ull);    // wq f16 *SCALE  (3072x2048)
  f16* wkvab = (f16*)take(1572864ull);    // wkv_a padded   (768x2048)
  f16* wkvbb = (f16*)take(2097152ull);    // wkv_b f16      (4096x512)
  f16* wob   = (f16*)take(4194304ull);    // wo f16         (2048x2048)
  f16* qraw  = (f16*)take(12582912ull);   // q proj, roped in epilogue (4096x3072)
  f16* kva   = (f16*)take(2621440ull);    // kv_a out       (4096x640)
  f16* kvn   = (f16*)take(2097152ull);    // rmsnormed kv   (4096x512)
  f16* kper  = (f16*)take(262144ull);     // roped k_pe     (4096x64)
  f16* knope = (f16*)take(8388608ull);    // k_nope         (4096x2048)
  f16* vf    = (f16*)take(8388608ull);    // V^T (b,h,128,2048)
  f16* aout  = (f16*)take(8388608ull);    // attn out       (4096x2048)

  k_cvt<<<22016, 256, 0, stream>>>(x, wq, wkvb, wo, wkva, xb, wqb, wkvbb, wob, wkvab);
  k_gemm_qkva<<<dim3(15, 16), 512, 0, stream>>>(xb, wqb, wkvab, cosb, sinb, qraw, kva);
  k_rmsnorm_rope<<<4096, 256, 0, stream>>>(kva, knw, cosb, sinb, kvn, kper);
  k_gemm_kvb<<<dim3(16, 16), 512, 0, stream>>>(kvn, wkvbb, knope, vf);
  k_attn<<<dim3(256), 512, 0, stream>>>(qraw, knope, kper, vf, aout);
  k_gemm_out<<<dim3(16, 32), 256, 0, stream>>>(aout, wob, out);
}